// Round 1
// baseline (333.532 us; speedup 1.0000x reference)
//
#include <hip/hip_runtime.h>
#include <hip/hip_bf16.h>

typedef float f32x4 __attribute__((ext_vector_type(4)));
typedef short bf16x8 __attribute__((ext_vector_type(8)));

#define MFMA_BF16 __builtin_amdgcn_mfma_f32_16x16x32_bf16

static __device__ __forceinline__ unsigned short f2bf(float f) {
    __hip_bfloat16 h = __float2bfloat16(f);
    return __builtin_bit_cast(unsigned short, h);
}
static __device__ __forceinline__ unsigned int pack2(float a, float b) {
    return (unsigned int)f2bf(a) | ((unsigned int)f2bf(b) << 16);
}

// ---------------------------------------------------------------------------
// Kernel 1: QKV projections. C_bf16 = cast_bf16(A_f32 @ W_f32 + b), written
// head-split: [B,H,L,64].  M=4096 (B*L), N=1024 (H*64), K=1024.
// 128x128 tile, 4 waves (2x2), BK=32, MFMA 16x16x32 bf16.
// ---------------------------------------------------------------------------
__global__ __launch_bounds__(256) void gemm_qkv(
    const float* __restrict__ q, const float* __restrict__ k, const float* __restrict__ v,
    const float* __restrict__ Wq, const float* __restrict__ Wk, const float* __restrict__ Wv,
    const float* __restrict__ bq, const float* __restrict__ bk, const float* __restrict__ bv,
    unsigned short* __restrict__ Qh, unsigned short* __restrict__ Kh, unsigned short* __restrict__ Vh)
{
    const float* A; const float* W; const float* bias; unsigned short* C;
    if (blockIdx.z == 0)      { A = q; W = Wq; bias = bq; C = Qh; }
    else if (blockIdx.z == 1) { A = k; W = Wk; bias = bk; C = Kh; }
    else                      { A = v; W = Wv; bias = bv; C = Vh; }

    const int n0 = blockIdx.x * 128;
    const int m0 = blockIdx.y * 128;
    const int t = threadIdx.x;
    const int wv = t >> 6, lane = t & 63, lrow = lane & 15, lkg = lane >> 4;
    const int wr = wv >> 1, wc = wv & 1;

    __shared__ unsigned short lA[128 * 40];   // [m][k], pad 32->40
    __shared__ unsigned short lB[128 * 40];   // [n][k] (W transposed)

    f32x4 acc[4][4];
#pragma unroll
    for (int i = 0; i < 4; i++)
#pragma unroll
        for (int j = 0; j < 4; j++) acc[i][j] = (f32x4){0.f, 0.f, 0.f, 0.f};

    const int ar = t >> 1, as = (t & 1) * 16;      // A staging: row, col-seg
    const int wk = t & 31, ns = (t >> 5) * 16;     // W staging: k-row, n-seg

    for (int k0 = 0; k0 < 1024; k0 += 32) {
        // stage A tile (fp32 -> bf16)
        const float4* asrc = (const float4*)&A[(size_t)(m0 + ar) * 1024 + k0 + as];
        float4 a0 = asrc[0], a1 = asrc[1], a2 = asrc[2], a3 = asrc[3];
        uint4 p0 = { pack2(a0.x, a0.y), pack2(a0.z, a0.w), pack2(a1.x, a1.y), pack2(a1.z, a1.w) };
        uint4 p1 = { pack2(a2.x, a2.y), pack2(a2.z, a2.w), pack2(a3.x, a3.y), pack2(a3.z, a3.w) };
        *(uint4*)&lA[ar * 40 + as]     = p0;
        *(uint4*)&lA[ar * 40 + as + 8] = p1;
        // stage W tile transposed ([n][k])
        const float4* wsrc = (const float4*)&W[(size_t)(k0 + wk) * 1024 + n0 + ns];
        float wf[16];
        *(float4*)&wf[0]  = wsrc[0];
        *(float4*)&wf[4]  = wsrc[1];
        *(float4*)&wf[8]  = wsrc[2];
        *(float4*)&wf[12] = wsrc[3];
#pragma unroll
        for (int j = 0; j < 16; j++) lB[(ns + j) * 40 + wk] = f2bf(wf[j]);

        __syncthreads();
        bf16x8 af[4], bfr[4];
#pragma unroll
        for (int mi = 0; mi < 4; mi++)
            af[mi] = *(const bf16x8*)&lA[(wr * 64 + mi * 16 + lrow) * 40 + lkg * 8];
#pragma unroll
        for (int ni = 0; ni < 4; ni++)
            bfr[ni] = *(const bf16x8*)&lB[(wc * 64 + ni * 16 + lrow) * 40 + lkg * 8];
#pragma unroll
        for (int mi = 0; mi < 4; mi++)
#pragma unroll
            for (int ni = 0; ni < 4; ni++)
                acc[mi][ni] = MFMA_BF16(af[mi], bfr[ni], acc[mi][ni], 0, 0, 0);
        __syncthreads();
    }

    // epilogue: bias + bf16 store to [B,H,L,64]
#pragma unroll
    for (int mi = 0; mi < 4; mi++) {
#pragma unroll
        for (int ni = 0; ni < 4; ni++) {
            int gn = n0 + wc * 64 + ni * 16 + lrow;
            float bb_ = bias[gn];
            int hh = gn >> 6, dk = gn & 63;
#pragma unroll
            for (int r = 0; r < 4; r++) {
                int gm = m0 + wr * 64 + mi * 16 + lkg * 4 + r;
                int bb = gm >> 11, ll = gm & 2047;
                C[(size_t)((bb * 16 + hh) * 2048 + ll) * 64 + dk] = f2bf(acc[mi][ni][r] + bb_);
            }
        }
    }
}

// ---------------------------------------------------------------------------
// Kernel 2: fused attention per (b,h) x 128-row Q-tile. 512 threads = 8 waves,
// each wave owns 16 Q rows. Sweep 1: row sums of exp(S) (no max needed: |S|<5).
// Sweep 2: recompute S, write normalized attn (fp32) + PV accumulate via LDS P.
// ---------------------------------------------------------------------------
__global__ __launch_bounds__(512) void attn_kernel(
    const unsigned short* __restrict__ Qh, const unsigned short* __restrict__ Kh,
    const unsigned short* __restrict__ Vh, float* __restrict__ attn,
    unsigned short* __restrict__ Oh)
{
    const int bh = blockIdx.y;            // b*16 + h
    const int b = bh >> 4, h = bh & 15;
    const int q0 = blockIdx.x * 128;
    const int t = threadIdx.x;
    const int w = t >> 6, lane = t & 63, lrow = lane & 15, lkg = lane >> 4;

    __shared__ unsigned short lKV[128 * 72];   // K: [j][72] ; V-T: [dv][136]
    __shared__ unsigned short lP[128 * 136];   // P tile [qrow][kcol]

    const size_t kvbase = (size_t)bh * 2048 * 64;
    const float scale = 0.125f;

    // Q fragments in registers (wave's 16 rows x 64 d)
    const unsigned short* qptr = Qh + kvbase + (size_t)(q0 + w * 16 + lrow) * 64;
    bf16x8 qf0 = *(const bf16x8*)(qptr + lkg * 8);
    bf16x8 qf1 = *(const bf16x8*)(qptr + 32 + lkg * 8);

    const int sr = t >> 2, ss = (t & 3) * 16;  // staging: row, 16-elem seg

    float lsum[4] = {0.f, 0.f, 0.f, 0.f};

    // ---- sweep 1: denominators ----
    for (int kt = 0; kt < 16; ++kt) {
        const int k0 = kt * 128;
        const uint4* ksrc = (const uint4*)(Kh + kvbase + (size_t)(k0 + sr) * 64 + ss);
        uint4 d0 = ksrc[0], d1 = ksrc[1];
        *(uint4*)&lKV[sr * 72 + ss]     = d0;
        *(uint4*)&lKV[sr * 72 + ss + 8] = d1;
        __syncthreads();
        f32x4 sacc[8];
#pragma unroll
        for (int ni = 0; ni < 8; ni++) sacc[ni] = (f32x4){0.f, 0.f, 0.f, 0.f};
#pragma unroll
        for (int ni = 0; ni < 8; ni++) {
            bf16x8 kf0 = *(const bf16x8*)&lKV[(ni * 16 + lrow) * 72 + lkg * 8];
            bf16x8 kf1 = *(const bf16x8*)&lKV[(ni * 16 + lrow) * 72 + 32 + lkg * 8];
            sacc[ni] = MFMA_BF16(qf0, kf0, sacc[ni], 0, 0, 0);
            sacc[ni] = MFMA_BF16(qf1, kf1, sacc[ni], 0, 0, 0);
        }
#pragma unroll
        for (int ni = 0; ni < 8; ni++)
#pragma unroll
            for (int r = 0; r < 4; r++)
                lsum[r] += __expf(sacc[ni][r] * scale);
        __syncthreads();
    }
#pragma unroll
    for (int r = 0; r < 4; r++) {
        lsum[r] += __shfl_xor(lsum[r], 1, 16);
        lsum[r] += __shfl_xor(lsum[r], 2, 16);
        lsum[r] += __shfl_xor(lsum[r], 4, 16);
        lsum[r] += __shfl_xor(lsum[r], 8, 16);
    }
    float inv_l[4];
#pragma unroll
    for (int r = 0; r < 4; r++) inv_l[r] = 1.0f / lsum[r];

    f32x4 acco[4];
#pragma unroll
    for (int nv = 0; nv < 4; nv++) acco[nv] = (f32x4){0.f, 0.f, 0.f, 0.f};

    // ---- sweep 2: attn write + PV ----
    for (int kt = 0; kt < 16; ++kt) {
        const int k0 = kt * 128;
        const uint4* ksrc = (const uint4*)(Kh + kvbase + (size_t)(k0 + sr) * 64 + ss);
        uint4 d0 = ksrc[0], d1 = ksrc[1];
        *(uint4*)&lKV[sr * 72 + ss]     = d0;
        *(uint4*)&lKV[sr * 72 + ss + 8] = d1;
        __syncthreads();
        f32x4 sacc[8];
#pragma unroll
        for (int ni = 0; ni < 8; ni++) sacc[ni] = (f32x4){0.f, 0.f, 0.f, 0.f};
#pragma unroll
        for (int ni = 0; ni < 8; ni++) {
            bf16x8 kf0 = *(const bf16x8*)&lKV[(ni * 16 + lrow) * 72 + lkg * 8];
            bf16x8 kf1 = *(const bf16x8*)&lKV[(ni * 16 + lrow) * 72 + 32 + lkg * 8];
            sacc[ni] = MFMA_BF16(qf0, kf0, sacc[ni], 0, 0, 0);
            sacc[ni] = MFMA_BF16(qf1, kf1, sacc[ni], 0, 0, 0);
        }
        // normalized P: fp32 -> global attn, bf16 -> LDS for PV
#pragma unroll
        for (int r = 0; r < 4; r++) {
            float* arow = attn + ((size_t)bh * 2048 + q0 + w * 16 + lkg * 4 + r) * 2048 + k0;
            const int prow = (w * 16 + lkg * 4 + r) * 136;
#pragma unroll
            for (int ni = 0; ni < 8; ni++) {
                float p = __expf(sacc[ni][r] * scale) * inv_l[r];
                arow[ni * 16 + lrow] = p;
                lP[prow + ni * 16 + lrow] = f2bf(p);
            }
        }
        __syncthreads();   // K reads + P writes done before V overwrites lKV
        // stage V transposed: lKV[dv][j]
        {
            const uint4* vsrc = (const uint4*)(Vh + kvbase + (size_t)(k0 + sr) * 64 + ss);
            uint4 v0 = vsrc[0], v1 = vsrc[1];
            unsigned short tmp[16];
            *(uint4*)&tmp[0] = v0;
            *(uint4*)&tmp[8] = v1;
#pragma unroll
            for (int e = 0; e < 16; e++) lKV[(ss + e) * 136 + sr] = tmp[e];
        }
        __syncthreads();
        // PV: out += P @ V
#pragma unroll
        for (int js = 0; js < 4; js++) {
            bf16x8 pf = *(const bf16x8*)&lP[(w * 16 + lrow) * 136 + js * 32 + lkg * 8];
#pragma unroll
            for (int nv = 0; nv < 4; nv++) {
                bf16x8 vf = *(const bf16x8*)&lKV[(nv * 16 + lrow) * 136 + js * 32 + lkg * 8];
                acco[nv] = MFMA_BF16(pf, vf, acco[nv], 0, 0, 0);
            }
        }
        __syncthreads();   // lP / lKV reused next iteration
    }

    // write O head-merged [B,L,H*64] bf16
#pragma unroll
    for (int nv = 0; nv < 4; nv++)
#pragma unroll
        for (int r = 0; r < 4; r++)
            Oh[(size_t)(b * 2048 + q0 + w * 16 + lkg * 4 + r) * 1024 + h * 64 + nv * 16 + lrow] =
                f2bf(acco[nv][r]);
}

// ---------------------------------------------------------------------------
// Kernel 3: output projection. out_f32 = Oh_bf16 @ Wo_f32 + bo. Same tile
// structure as gemm_qkv, bf16 A staging, fp32 row-major output.
// ---------------------------------------------------------------------------
__global__ __launch_bounds__(256) void gemm_out(
    const unsigned short* __restrict__ A, const float* __restrict__ W,
    const float* __restrict__ bias, float* __restrict__ C)
{
    const int n0 = blockIdx.x * 128;
    const int m0 = blockIdx.y * 128;
    const int t = threadIdx.x;
    const int wv = t >> 6, lane = t & 63, lrow = lane & 15, lkg = lane >> 4;
    const int wr = wv >> 1, wc = wv & 1;

    __shared__ unsigned short lA[128 * 40];
    __shared__ unsigned short lB[128 * 40];

    f32x4 acc[4][4];
#pragma unroll
    for (int i = 0; i < 4; i++)
#pragma unroll
        for (int j = 0; j < 4; j++) acc[i][j] = (f32x4){0.f, 0.f, 0.f, 0.f};

    const int ar = t >> 1, as = (t & 1) * 16;
    const int wk = t & 31, ns = (t >> 5) * 16;

    for (int k0 = 0; k0 < 1024; k0 += 32) {
        const uint4* asrc = (const uint4*)&A[(size_t)(m0 + ar) * 1024 + k0 + as];
        uint4 p0 = asrc[0], p1 = asrc[1];
        *(uint4*)&lA[ar * 40 + as]     = p0;
        *(uint4*)&lA[ar * 40 + as + 8] = p1;
        const float4* wsrc = (const float4*)&W[(size_t)(k0 + wk) * 1024 + n0 + ns];
        float wf[16];
        *(float4*)&wf[0]  = wsrc[0];
        *(float4*)&wf[4]  = wsrc[1];
        *(float4*)&wf[8]  = wsrc[2];
        *(float4*)&wf[12] = wsrc[3];
#pragma unroll
        for (int j = 0; j < 16; j++) lB[(ns + j) * 40 + wk] = f2bf(wf[j]);

        __syncthreads();
        bf16x8 af[4], bfr[4];
#pragma unroll
        for (int mi = 0; mi < 4; mi++)
            af[mi] = *(const bf16x8*)&lA[(wr * 64 + mi * 16 + lrow) * 40 + lkg * 8];
#pragma unroll
        for (int ni = 0; ni < 4; ni++)
            bfr[ni] = *(const bf16x8*)&lB[(wc * 64 + ni * 16 + lrow) * 40 + lkg * 8];
#pragma unroll
        for (int mi = 0; mi < 4; mi++)
#pragma unroll
            for (int ni = 0; ni < 4; ni++)
                acc[mi][ni] = MFMA_BF16(af[mi], bfr[ni], acc[mi][ni], 0, 0, 0);
        __syncthreads();
    }

#pragma unroll
    for (int mi = 0; mi < 4; mi++) {
#pragma unroll
        for (int ni = 0; ni < 4; ni++) {
            int gn = n0 + wc * 64 + ni * 16 + lrow;
            float bb_ = bias[gn];
#pragma unroll
            for (int r = 0; r < 4; r++) {
                int gm = m0 + wr * 64 + mi * 16 + lkg * 4 + r;
                C[(size_t)gm * 1024 + gn] = acc[mi][ni][r] + bb_;
            }
        }
    }
}

// ---------------------------------------------------------------------------
extern "C" void kernel_launch(void* const* d_in, const int* in_sizes, int n_in,
                              void* d_out, int out_size, void* d_ws, size_t ws_size,
                              hipStream_t stream) {
    const float* q  = (const float*)d_in[0];
    const float* k  = (const float*)d_in[1];
    const float* v  = (const float*)d_in[2];
    const float* Wq = (const float*)d_in[3];
    const float* bq = (const float*)d_in[4];
    const float* Wk = (const float*)d_in[5];
    const float* bk = (const float*)d_in[6];
    const float* Wv = (const float*)d_in[7];
    const float* bv = (const float*)d_in[8];
    const float* Wo = (const float*)d_in[9];
    const float* bo = (const float*)d_in[10];

    float* out  = (float*)d_out;                    // [2,2048,1024]
    float* attn = out + (size_t)2 * 2048 * 1024;    // [2,16,2048,2048]

    const size_t HS = (size_t)2 * 16 * 2048 * 64;   // 4,194,304 bf16 elems
    unsigned short* Qh = (unsigned short*)d_ws;
    unsigned short* Kh = Qh + HS;
    unsigned short* Vh = Kh + HS;
    unsigned short* Oh = Vh + HS;                   // [B,L,1024] bf16

    gemm_qkv<<<dim3(8, 32, 3), 256, 0, stream>>>(q, k, v, Wq, Wk, Wv, bq, bk, bv, Qh, Kh, Vh);
    attn_kernel<<<dim3(16, 32), 512, 0, stream>>>(Qh, Kh, Vh, attn, Oh);
    gemm_out<<<dim3(8, 32), 256, 0, stream>>>(Oh, Wo, bo, out);
}